// Round 13
// baseline (128.910 us; speedup 1.0000x reference)
//
#include <hip/hip_runtime.h>

// Problem constants: features [C=32, N], coords [N,3]=(b,h,w),
// output [B=64, C=32, NH=64, NW=256] float32.
#define CC 32
#define BB 64
#define NHH 64
#define NWW 256
#define PLANE (NHH * NWW)        // 16384 cells per batch
#define BSTRIDE (CC * PLANE)     // 524288 floats per batch in out
#define NCELLS (BB * PLANE)      // 1048576 total cells
#define LSTRIDE 67               // LDS row stride (dwords): 2-way banks both phases

typedef float f32x4 __attribute__((ext_vector_type(4)));  // clang vector: builtin-legal

// ---------- Fallback (round-1) direct scatter ----------
__global__ void pss_scatter_direct(const float* __restrict__ features,
                                   const int* __restrict__ coords,
                                   float* __restrict__ out, int N) {
    int n = blockIdx.x * blockDim.x + threadIdx.x;
    if (n >= N) return;
    int b = coords[3 * n + 0];
    int h = coords[3 * n + 1];
    int w = coords[3 * n + 2];
    int base = b * BSTRIDE + h * NWW + w;
#pragma unroll
    for (int c = 0; c < CC; ++c)
        out[base + c * PLANE] = features[c * N + n];
}

// ---------- K-1: zero invmap ----------
__global__ __launch_bounds__(256) void pss_zero(int4* __restrict__ p, int n4) {
    int i = blockIdx.x * blockDim.x + threadIdx.x;
    if (i < n4) p[i] = make_int4(0, 0, 0, 0);
}

// ---------- K1: wave-private LDS transpose + fused invmap ----------
// features [C][N] -> featT [N][C]; invmap[cell] = n+1.
// Read side VECTORIZED (G13): lane l = (m=l&15 quad, g=l>>4 group);
// instr k loads float4 of channel c=4k+g at n0+4m -> 8 instrs x 1KB/wave
// (was 32 x 256B scalar). LDS stride 67: scalar ds_write bank =
// (3c+4m+e)%32 -> 2-way (free); phase-3 read bank = (12cq+3e+nl)%32 -> 2-way.
// No __syncthreads (wave-private tile). Stores: float4, lanes contiguous,
// 1KB/instr, destination sequential in n.
__global__ __launch_bounds__(256) void pss_transpose_wp2(
        const float* __restrict__ features, const int* __restrict__ coords,
        float* __restrict__ featT, int* __restrict__ invmap, int N) {
    __shared__ float lds[4 * CC * LSTRIDE];  // 4 waves * 32 * 67 * 4B = 34304 B

    int lane = threadIdx.x & 63;
    int wid = threadIdx.x >> 6;
    int n0 = blockIdx.x * 256 + wid * 64;  // wave's base n
    if (n0 >= N) return;                   // whole-wave exit; no barriers

    float* wl = &lds[wid * CC * LSTRIDE];

    // Fused invmap scatter: lane handles n = n0 + lane.
    int n = n0 + lane;
    if (n < N) {
        int b = coords[3 * n + 0];
        int h = coords[3 * n + 1];
        int w = coords[3 * n + 2];
        invmap[b * PLANE + h * NWW + w] = n + 1;  // random 4B into 4MB (L3)
    }

    // Phase 1: 8 float4 loads, 16B/lane (nontemporal: read-once).
    int m = lane & 15;          // n-quad within tile: n = n0 + 4m .. +3
    int g = lane >> 4;          // channel sub-index
    int nq = n0 + 4 * m;
    bool okq = (nq + 3 < N);    // N%4==0 in this problem
    f32x4 f4[8];
#pragma unroll
    for (int k = 0; k < 8; ++k) {
        int c = 4 * k + g;
        if (okq)
            f4[k] = __builtin_nontemporal_load(
                (const f32x4*)&features[(size_t)c * N + nq]);
        else
            f4[k] = (f32x4){0.f, 0.f, 0.f, 0.f};
    }

    // Phase 2: scalar LDS writes (odd stride -> keep b32; 2-way banks = free).
#pragma unroll
    for (int k = 0; k < 8; ++k) {
        int c = 4 * k + g;
        wl[c * LSTRIDE + 4 * m + 0] = f4[k].x;
        wl[c * LSTRIDE + 4 * m + 1] = f4[k].y;
        wl[c * LSTRIDE + 4 * m + 2] = f4[k].z;
        wl[c * LSTRIDE + 4 * m + 3] = f4[k].w;
    }

    // Phase 3: transposed read + linear float4 store (1KB/instr, sequential).
    float4* dstv = (float4*)featT;
    int cq = lane & 7;
    int nlb = lane >> 3;
#pragma unroll
    for (int j = 0; j < 8; ++j) {
        int nl = nlb + 8 * j;
        if (n0 + nl < N) {
            float4 v;
            v.x = wl[(4 * cq + 0) * LSTRIDE + nl];
            v.y = wl[(4 * cq + 1) * LSTRIDE + nl];
            v.z = wl[(4 * cq + 2) * LSTRIDE + nl];
            v.w = wl[(4 * cq + 3) * LSTRIDE + nl];
            dstv[(size_t)n0 * 8 + lane + 64 * j] = v;
        }
    }
}

// ---------- K2: gather featT rows per cell, emit out coalesced ----------
// featT rows random but L3-resident. out stores nontemporal (write-once
// stream; don't evict featT).
__global__ __launch_bounds__(256) void pss_gather_emit(
        const float* __restrict__ featT, const int* __restrict__ invmap,
        float* __restrict__ out) {
    __shared__ float lds[NWW * (CC + 1)];  // 256 * 33 floats

    int row = blockIdx.x;          // 0 .. B*NH-1  (row = b*NHH + h)
    int b = row / NHH;
    int h = row % NHH;
    int t = threadIdx.x;           // 0..255 = w

    int inv = invmap[(size_t)row * NWW + t];  // coalesced 1KB per block

    if (inv > 0) {
        const float4* src = (const float4*)(featT + (size_t)(inv - 1) * CC);
#pragma unroll
        for (int k = 0; k < CC / 4; ++k) {
            float4 v = src[k];
            lds[t * (CC + 1) + 4 * k + 0] = v.x;
            lds[t * (CC + 1) + 4 * k + 1] = v.y;
            lds[t * (CC + 1) + 4 * k + 2] = v.z;
            lds[t * (CC + 1) + 4 * k + 3] = v.w;
        }
    } else {
#pragma unroll
        for (int k = 0; k < CC; ++k)
            lds[t * (CC + 1) + k] = 0.0f;
    }

    __syncthreads();

    size_t obase = (size_t)b * BSTRIDE + (size_t)h * NWW + t;
#pragma unroll
    for (int c = 0; c < CC; ++c) {
        float v = lds[t * (CC + 1) + c];  // bank (t+c)%32 -> conflict-free
        __builtin_nontemporal_store(v, &out[obase + (size_t)c * PLANE]);
    }
}

extern "C" void kernel_launch(void* const* d_in, const int* in_sizes, int n_in,
                              void* d_out, int out_size, void* d_ws, size_t ws_size,
                              hipStream_t stream) {
    const float* features = (const float*)d_in[0];
    const int* coords = (const int*)d_in[1];
    float* out = (float*)d_out;
    const int N = in_sizes[1] / 3;

    const size_t invmap_bytes = (size_t)NCELLS * sizeof(int);       // 4 MiB
    const size_t featT_bytes = (size_t)N * CC * sizeof(float);      // ~115 MB

    if (ws_size < invmap_bytes + featT_bytes) {
        // Fallback: direct scatter (correct, slower).
        (void)hipMemsetAsync(d_out, 0, (size_t)out_size * sizeof(float), stream);
        int blocks = (N + 255) / 256;
        pss_scatter_direct<<<blocks, 256, 0, stream>>>(features, coords, out, N);
        return;
    }

    int* invmap = (int*)d_ws;
    float* featT = (float*)((char*)d_ws + invmap_bytes);

    // Zero invmap (0 == empty cell).
    pss_zero<<<(NCELLS / 4 + 255) / 256, 256, 0, stream>>>((int4*)invmap,
                                                           NCELLS / 4);

    pss_transpose_wp2<<<(N + 255) / 256, 256, 0, stream>>>(features, coords,
                                                           featT, invmap, N);

    pss_gather_emit<<<BB * NHH, 256, 0, stream>>>(featT, invmap, out);
}

// Round 14
// 99.521 us; speedup vs baseline: 1.2953x; 1.2953x over previous
//
#include <hip/hip_runtime.h>

// Problem constants: features [C=32, N], coords [N,3]=(b,h,w),
// output [B=64, C=32, NH=64, NW=256] float32.
#define CC 32
#define BB 64
#define NHH 64
#define NWW 256
#define PLANE (NHH * NWW)        // 16384 cells per batch
#define BSTRIDE (CC * PLANE)     // 524288 floats per batch in out
#define NCELLS (BB * PLANE)      // 1048576 total cells
#define TGRID 1024               // persistent transpose blocks (4/CU, LDS-capped)

// ---------- Fallback (round-1) direct scatter ----------
__global__ void pss_scatter_direct(const float* __restrict__ features,
                                   const int* __restrict__ coords,
                                   float* __restrict__ out, int N) {
    int n = blockIdx.x * blockDim.x + threadIdx.x;
    if (n >= N) return;
    int b = coords[3 * n + 0];
    int h = coords[3 * n + 1];
    int w = coords[3 * n + 2];
    int base = b * BSTRIDE + h * NWW + w;
#pragma unroll
    for (int c = 0; c < CC; ++c)
        out[base + c * PLANE] = features[c * N + n];
}

// ---------- K-1: zero invmap ----------
__global__ __launch_bounds__(256) void pss_zero(int4* __restrict__ p, int n4) {
    int i = blockIdx.x * blockDim.x + threadIdx.x;
    if (i < n4) p[i] = make_int4(0, 0, 0, 0);
}

// ---------- K0: invmap scatter (tiny): invmap[cell] = n+1 ----------
__global__ void pss_invmap(const int* __restrict__ coords,
                           int* __restrict__ invmap, int N) {
    int n = blockIdx.x * blockDim.x + threadIdx.x;
    if (n >= N) return;
    int b = coords[3 * n + 0];
    int h = coords[3 * n + 1];
    int w = coords[3 * n + 2];
    invmap[b * PLANE + h * NWW + w] = n + 1;
}

// ---------- K1: persistent pipelined wave-private transpose ----------
// features [C][N] -> featT [N][C]. Memory patterns = round-11 wp (proven:
// 0 bank conflicts, clean request streams):
//   loads : 32 scalar NT loads/thread, 256B contiguous per instr
//   LDS   : wave-private 64n x 32c tile, stride 66 (2-way = free)
//   stores: 8x float4, lanes contiguous (1KB/instr), sequential in n
// NEW: 1024 persistent blocks (exactly 4/CU); each wave grid-strides over
// tiles with a manual pipeline: ds_write(cur) -> issue next tile's 32 loads
// -> ds_read+store(cur). Next tile's 8KB of loads fly under the current
// tile's LDS+store phase; block launch/drain paid 1024x not 3516x.
// No __syncthreads anywhere (wave-private tile; DS ops are in-order per wave).
__global__ __launch_bounds__(256) void pss_transpose_pp(
        const float* __restrict__ features, float* __restrict__ featT,
        int N, int ntiles) {
    __shared__ float lds[4 * CC * 66];  // 4 waves * 32c * (64n + 2 pad) = 33792 B

    int lane = threadIdx.x & 63;
    int wid = threadIdx.x >> 6;
    float* wl = &lds[wid * CC * 66];

    const int nwaves = TGRID * 4;            // total waves in grid
    int T = blockIdx.x * 4 + wid;            // this wave's first tile
    if (T >= ntiles) return;

    float f[CC];

    // Prologue: load tile T into registers.
    {
        int n = T * 64 + lane;
        bool ok = (n < N);
#pragma unroll
        for (int c = 0; c < CC; ++c)
            f[c] = ok ? __builtin_nontemporal_load(&features[(size_t)c * N + n])
                      : 0.0f;
    }

    float4* dstv = (float4*)featT;
    int cq = lane & 7;
    int nlb = lane >> 3;

    while (true) {
        // Stage current tile's registers into LDS (c-major; 2 lanes/bank = free).
#pragma unroll
        for (int c = 0; c < CC; ++c)
            wl[c * 66 + lane] = f[c];

        // Issue next tile's 32 loads NOW — they complete under the LDS+store
        // phase below (ds_write latched f at issue; regs safely reusable).
        int Tn = T + nwaves;
        if (Tn < ntiles) {
            int n = Tn * 64 + lane;
            bool ok = (n < N);
#pragma unroll
            for (int c = 0; c < CC; ++c)
                f[c] = ok ? __builtin_nontemporal_load(
                                &features[(size_t)c * N + n])
                          : 0.0f;
        }

        // Transposed read + linear float4 store for tile T (1KB/instr).
        // Read bank = (2(4cq+e) + nl) % 32 -> 2 lanes/bank (free).
        int n0 = T * 64;
#pragma unroll
        for (int j = 0; j < 8; ++j) {
            int nl = nlb + 8 * j;
            if (n0 + nl < N) {
                float4 v;
                v.x = wl[(4 * cq + 0) * 66 + nl];
                v.y = wl[(4 * cq + 1) * 66 + nl];
                v.z = wl[(4 * cq + 2) * 66 + nl];
                v.w = wl[(4 * cq + 3) * 66 + nl];
                // normal store (NOT nontemporal): featT must stay L3-resident
                // for the gather's random row reads.
                dstv[(size_t)n0 * 8 + lane + 64 * j] = v;
            }
        }

        if (Tn >= ntiles) break;
        T = Tn;
    }
}

// ---------- K2: gather featT rows per cell, emit out coalesced ----------
// featT rows random but L3-resident. out stores nontemporal (write-once
// stream; don't evict featT).
__global__ __launch_bounds__(256) void pss_gather_emit(
        const float* __restrict__ featT, const int* __restrict__ invmap,
        float* __restrict__ out) {
    __shared__ float lds[NWW * (CC + 1)];  // 256 * 33 floats

    int row = blockIdx.x;          // 0 .. B*NH-1  (row = b*NHH + h)
    int b = row / NHH;
    int h = row % NHH;
    int t = threadIdx.x;           // 0..255 = w

    int inv = invmap[(size_t)row * NWW + t];  // coalesced 1KB per block

    if (inv > 0) {
        const float4* src = (const float4*)(featT + (size_t)(inv - 1) * CC);
#pragma unroll
        for (int k = 0; k < CC / 4; ++k) {
            float4 v = src[k];
            lds[t * (CC + 1) + 4 * k + 0] = v.x;
            lds[t * (CC + 1) + 4 * k + 1] = v.y;
            lds[t * (CC + 1) + 4 * k + 2] = v.z;
            lds[t * (CC + 1) + 4 * k + 3] = v.w;
        }
    } else {
#pragma unroll
        for (int k = 0; k < CC; ++k)
            lds[t * (CC + 1) + k] = 0.0f;
    }

    __syncthreads();

    size_t obase = (size_t)b * BSTRIDE + (size_t)h * NWW + t;
#pragma unroll
    for (int c = 0; c < CC; ++c) {
        float v = lds[t * (CC + 1) + c];  // bank (t+c)%32 -> conflict-free
        __builtin_nontemporal_store(v, &out[obase + (size_t)c * PLANE]);
    }
}

extern "C" void kernel_launch(void* const* d_in, const int* in_sizes, int n_in,
                              void* d_out, int out_size, void* d_ws, size_t ws_size,
                              hipStream_t stream) {
    const float* features = (const float*)d_in[0];
    const int* coords = (const int*)d_in[1];
    float* out = (float*)d_out;
    const int N = in_sizes[1] / 3;

    const size_t invmap_bytes = (size_t)NCELLS * sizeof(int);       // 4 MiB
    const size_t featT_bytes = (size_t)N * CC * sizeof(float);      // ~115 MB

    if (ws_size < invmap_bytes + featT_bytes) {
        // Fallback: direct scatter (correct, slower).
        (void)hipMemsetAsync(d_out, 0, (size_t)out_size * sizeof(float), stream);
        int blocks = (N + 255) / 256;
        pss_scatter_direct<<<blocks, 256, 0, stream>>>(features, coords, out, N);
        return;
    }

    int* invmap = (int*)d_ws;
    float* featT = (float*)((char*)d_ws + invmap_bytes);

    // Zero invmap (0 == empty cell).
    pss_zero<<<(NCELLS / 4 + 255) / 256, 256, 0, stream>>>((int4*)invmap,
                                                           NCELLS / 4);

    pss_invmap<<<(N + 255) / 256, 256, 0, stream>>>(coords, invmap, N);

    int ntiles = (N + 63) / 64;
    pss_transpose_pp<<<TGRID, 256, 0, stream>>>(features, featT, N, ntiles);

    pss_gather_emit<<<BB * NHH, 256, 0, stream>>>(featT, invmap, out);
}